// Round 3
// baseline (880.032 us; speedup 1.0000x reference)
//
#include <hip/hip_runtime.h>
#include <hip/hip_bf16.h>

#define N_NODES 50000
#define N_EDGES 800000
#define D 128
#define D2 64  // element-pairs per row

static constexpr float SLOPE = 11.0f / 48.0f;  // eval-mode RReLU mean slope

typedef __attribute__((ext_vector_type(8))) short bf16x8;
typedef __attribute__((ext_vector_type(4))) float f32x4;

__device__ __forceinline__ float bf_lo(unsigned int v) { return __uint_as_float(v << 16); }
__device__ __forceinline__ float bf_hi(unsigned int v) { return __uint_as_float(v & 0xffff0000u); }

__device__ __forceinline__ unsigned short f2bf(float x) {
    __hip_bfloat16 b = __float2bfloat16(x);
    return *(unsigned short*)&b;
}

__device__ __forceinline__ unsigned int pack_bf2(float lo, float hi) {
    return ((unsigned int)f2bf(hi) << 16) | (unsigned int)f2bf(lo);
}

// convert 8 contiguous fp32 to a bf16x8 MFMA fragment
__device__ __forceinline__ bf16x8 cvt8(const float* __restrict__ p) {
    f32x4 lo = *(const f32x4*)p;
    f32x4 hi = *(const f32x4*)(p + 4);
    bf16x8 r;
#pragma unroll
    for (int i = 0; i < 4; ++i) r[i] = (short)f2bf(lo[i]);
#pragma unroll
    for (int i = 0; i < 4; ++i) r[4 + i] = (short)f2bf(hi[i]);
    return r;
}

// ---------------- CSR build ----------------

__global__ void k_count(const int* __restrict__ dst, int* __restrict__ deg) {
    int e = blockIdx.x * 256 + threadIdx.x;
    if (e < N_EDGES) atomicAdd(&deg[dst[e]], 1);
}

__global__ void k_scan1(const int* __restrict__ deg, int* __restrict__ offs,
                        int* __restrict__ part) {
    __shared__ int sm[256];
    int t = threadIdx.x;
    int i = blockIdx.x * 256 + t;
    int v = (i < N_NODES) ? deg[i] : 0;
    int orig = v;
    sm[t] = v;
    __syncthreads();
    for (int off = 1; off < 256; off <<= 1) {
        int x = (t >= off) ? sm[t - off] : 0;
        __syncthreads();
        sm[t] += x;
        __syncthreads();
    }
    if (i < N_NODES) offs[i] = sm[t] - orig;  // exclusive within block
    if (t == 255) part[blockIdx.x] = sm[t];   // block total
}

__global__ void k_scan2(int* __restrict__ part, int nb) {
    __shared__ int sm[256];
    int t = threadIdx.x;
    int v = (t < nb) ? part[t] : 0;
    int orig = v;
    sm[t] = v;
    __syncthreads();
    for (int off = 1; off < 256; off <<= 1) {
        int x = (t >= off) ? sm[t - off] : 0;
        __syncthreads();
        sm[t] += x;
        __syncthreads();
    }
    if (t < nb) part[t] = sm[t] - orig;  // exclusive block offsets
}

__global__ void k_scan3(int* __restrict__ offs, const int* __restrict__ part) {
    int i = blockIdx.x * 256 + threadIdx.x;
    if (i < N_NODES) offs[i] += part[blockIdx.x];
}

__global__ void k_fill(const int* __restrict__ src, const int* __restrict__ dst,
                       const int* __restrict__ offs, int* __restrict__ cur,
                       int2* __restrict__ csr) {
    int e = blockIdx.x * 256 + threadIdx.x;
    if (e < N_EDGES) {
        int d = dst[e];
        int p = offs[d] + atomicAdd(&cur[d], 1);
        csr[p] = make_int2(src[e], e);  // (src node, edge id)
    }
}

// ---------------- layer-1 aggregation (fp32 in, bf16 out) ----------------
// efsum[n] = sum edge_feats over in-edges (bf16-packed, reused by layer 2)
// pre[n]   = (sum h[src] + efsum[n]) / max(deg,1)   (bf16-packed)

__global__ void k_agg_ef(const float2* __restrict__ h,   // fp32 [N,128]
                         const float2* __restrict__ ef,  // fp32 [E,128]
                         const int2* __restrict__ csr,
                         const int* __restrict__ offs, const int* __restrict__ deg,
                         unsigned int* __restrict__ efsum,
                         unsigned int* __restrict__ pre) {
    int node = blockIdx.x * 4 + (threadIdx.x >> 6);
    if (node >= N_NODES) return;
    int lane = threadIdx.x & 63;
    int start = offs[node];
    int cnt = deg[node];
    float hx = 0.f, hy = 0.f, ex = 0.f, ey = 0.f;
    for (int k = 0; k < cnt; ++k) {
        int2 se = csr[start + k];
        float2 hv = h[(size_t)se.x * D2 + lane];
        float2 ev = ef[(size_t)se.y * D2 + lane];
        hx += hv.x;
        hy += hv.y;
        ex += ev.x;
        ey += ev.y;
    }
    efsum[(size_t)node * D2 + lane] = pack_bf2(ex, ey);
    float inv = 1.0f / fmaxf((float)cnt, 1.0f);
    pre[(size_t)node * D2 + lane] = pack_bf2((hx + ex) * inv, (hy + ey) * inv);
}

// ---------------- layer-2 aggregation (bf16 h1 table) ----------------

__global__ void k_agg2(const unsigned int* __restrict__ h,  // bf16x2 [N*64]
                       const int2* __restrict__ csr,
                       const int* __restrict__ offs, const int* __restrict__ deg,
                       const unsigned int* __restrict__ efsum,
                       unsigned int* __restrict__ pre) {
    int node = blockIdx.x * 4 + (threadIdx.x >> 6);
    if (node >= N_NODES) return;
    int lane = threadIdx.x & 63;
    int start = offs[node];
    int cnt = deg[node];
    unsigned int es = efsum[(size_t)node * D2 + lane];
    float ax = bf_lo(es), ay = bf_hi(es);
    for (int k = 0; k < cnt; ++k) {
        int2 se = csr[start + k];
        unsigned int v = h[(size_t)se.x * D2 + lane];
        ax += bf_lo(v);
        ay += bf_hi(v);
    }
    float inv = 1.0f / fmaxf((float)cnt, 1.0f);
    pre[(size_t)node * D2 + lane] = pack_bf2(ax * inv, ay * inv);
}

// ---------------- fused GEMM: out = leaky(pre@Wn^T + h@Ws^T) ----------------
// NT GEMM, M=50000, N=128, K=256 ([pre|h] @ [Wn|Ws]^T). A1 = pre (bf16).
// A2 = layer's h (fp32 for layer 1, bf16 for layer 2). W fp32, converted
// in-register. Compute in bf16 MFMA 16x16x32, fp32 accumulate.

template <int A2_F32, int OUT_F32>
__global__ void k_gemm(const unsigned short* __restrict__ A1,  // pre [M,128] bf16
                       const void* __restrict__ A2v,           // h [M,128]
                       const float* __restrict__ W1,           // Wn [128,128] fp32
                       const float* __restrict__ W2,           // Ws [128,128] fp32
                       void* __restrict__ outv) {
    int wave = threadIdx.x >> 6;
    int lane = threadIdx.x & 63;
    int quad = lane >> 4;
    int r16 = lane & 15;
    int m0 = (blockIdx.x * 4 + wave) * 32;  // 32 rows per wave (2 m-tiles)

    f32x4 acc[2][8];
#pragma unroll
    for (int mt = 0; mt < 2; ++mt)
#pragma unroll
        for (int nt = 0; nt < 8; ++nt) acc[mt][nt] = (f32x4){0.f, 0.f, 0.f, 0.f};

    int rowA0 = min(m0 + r16, N_NODES - 1);
    int rowA1 = min(m0 + 16 + r16, N_NODES - 1);

#pragma unroll
    for (int ks = 0; ks < 8; ++ks) {
        int koff = (ks & 3) * 32 + quad * 8;  // lane's 8 contiguous k
        bf16x8 a0, a1;
        if (ks < 4) {
            a0 = *(const bf16x8*)(A1 + (size_t)rowA0 * D + koff);
            a1 = *(const bf16x8*)(A1 + (size_t)rowA1 * D + koff);
        } else if (A2_F32) {
            const float* A2 = (const float*)A2v;
            a0 = cvt8(A2 + (size_t)rowA0 * D + koff);
            a1 = cvt8(A2 + (size_t)rowA1 * D + koff);
        } else {
            const unsigned short* A2 = (const unsigned short*)A2v;
            a0 = *(const bf16x8*)(A2 + (size_t)rowA0 * D + koff);
            a1 = *(const bf16x8*)(A2 + (size_t)rowA1 * D + koff);
        }
        const float* Wsrc = (ks < 4) ? W1 : W2;
#pragma unroll
        for (int nt = 0; nt < 8; ++nt) {
            bf16x8 b = cvt8(Wsrc + (size_t)(nt * 16 + r16) * D + koff);
            acc[0][nt] = __builtin_amdgcn_mfma_f32_16x16x32_bf16(a0, b, acc[0][nt], 0, 0, 0);
            acc[1][nt] = __builtin_amdgcn_mfma_f32_16x16x32_bf16(a1, b, acc[1][nt], 0, 0, 0);
        }
    }

    // C/D layout: col = lane&15, row = quad*4 + reg (m89/m91-verified)
#pragma unroll
    for (int mt = 0; mt < 2; ++mt) {
#pragma unroll
        for (int r = 0; r < 4; ++r) {
            int row = m0 + mt * 16 + quad * 4 + r;
            if (row < N_NODES) {
#pragma unroll
                for (int nt = 0; nt < 8; ++nt) {
                    float x = acc[mt][nt][r];
                    x = (x >= 0.f) ? x : x * SLOPE;
                    if (OUT_F32)
                        ((float*)outv)[(size_t)row * D + nt * 16 + r16] = x;
                    else
                        ((unsigned short*)outv)[(size_t)row * D + nt * 16 + r16] = f2bf(x);
                }
            }
        }
    }
}

// iso nodes (deg==0): out[n] = leaky(h[n] @ Wi^T). Expected ~0 such nodes.
// Overwrites the GEMM's value for those rows.

__global__ void k_fixup1(const float* __restrict__ h,   // node_feats fp32
                         const float* __restrict__ Wi,  // fp32
                         const int* __restrict__ deg,
                         unsigned short* __restrict__ out) {  // h1 bf16
    int node = blockIdx.x * 4 + (threadIdx.x >> 6);
    if (node >= N_NODES) return;
    if (deg[node] != 0) return;  // wave-uniform exit
    int lane = threadIdx.x & 63;
    float a0 = 0.f, a1 = 0.f;
    const float* hrow = h + (size_t)node * D;
    for (int k = 0; k < D; ++k) {
        float hk = hrow[k];
        a0 += hk * Wi[(size_t)lane * D + k];
        a1 += hk * Wi[(size_t)(lane + 64) * D + k];
    }
    a0 = (a0 >= 0.f) ? a0 : a0 * SLOPE;
    a1 = (a1 >= 0.f) ? a1 : a1 * SLOPE;
    out[(size_t)node * D + lane] = f2bf(a0);
    out[(size_t)node * D + lane + 64] = f2bf(a1);
}

__global__ void k_fixup2(const unsigned short* __restrict__ h,  // h1 bf16
                         const float* __restrict__ Wi,          // fp32
                         const int* __restrict__ deg,
                         float* __restrict__ out) {  // d_out fp32
    int node = blockIdx.x * 4 + (threadIdx.x >> 6);
    if (node >= N_NODES) return;
    if (deg[node] != 0) return;  // wave-uniform exit
    int lane = threadIdx.x & 63;
    float a0 = 0.f, a1 = 0.f;
    const unsigned short* hrow = h + (size_t)node * D;
    for (int k = 0; k < D; ++k) {
        float hk = __uint_as_float(((unsigned int)hrow[k]) << 16);
        a0 += hk * Wi[(size_t)lane * D + k];
        a1 += hk * Wi[(size_t)(lane + 64) * D + k];
    }
    a0 = (a0 >= 0.f) ? a0 : a0 * SLOPE;
    a1 = (a1 >= 0.f) ? a1 : a1 * SLOPE;
    out[(size_t)node * D + lane] = a0;
    out[(size_t)node * D + lane + 64] = a1;
}

// ---------------- launch ----------------

extern "C" void kernel_launch(void* const* d_in, const int* in_sizes, int n_in,
                              void* d_out, int out_size, void* d_ws, size_t ws_size,
                              hipStream_t stream) {
    const float* node_feats = (const float*)d_in[0];
    const float* edge_feats = (const float*)d_in[1];
    const int* src = (const int*)d_in[2];
    const int* dst = (const int*)d_in[3];
    const float* Wn0 = (const float*)d_in[4];
    const float* Ws0 = (const float*)d_in[5];
    const float* Wi0 = (const float*)d_in[6];
    const float* Wn1 = (const float*)d_in[7];
    const float* Ws1 = (const float*)d_in[8];
    const float* Wi1 = (const float*)d_in[9];

    char* ws = (char*)d_ws;
    size_t o = 0;
    auto alloc = [&](size_t bytes) -> char* {
        char* p = ws + o;
        o += (bytes + 255) & ~size_t(255);
        return p;
    };
    int* deg = (int*)alloc((size_t)N_NODES * 4);            // 200192 B
    int* cur = (int*)alloc((size_t)N_NODES * 4);            // 200192 B
    int* offs = (int*)alloc((size_t)N_NODES * 4);           // 200192 B
    int* part = (int*)alloc(1024);
    int2* csr = (int2*)alloc((size_t)N_EDGES * 8);                        //  6.4 MB
    unsigned int* efsum = (unsigned int*)alloc((size_t)N_NODES * D * 2);  // 12.8 MB
    unsigned int* pre = (unsigned int*)alloc((size_t)N_NODES * D * 2);    // 12.8 MB
    unsigned int* h1 = (unsigned int*)alloc((size_t)N_NODES * D * 2);     // 12.8 MB
    // total ~45.5 MiB

    // zero deg + cur (contiguous allocations)
    hipMemsetAsync(deg, 0, 2 * (((size_t)N_NODES * 4 + 255) & ~size_t(255)), stream);

    int ebl = (N_EDGES + 255) / 256;   // 3125
    int nbl = (N_NODES + 255) / 256;   // 196
    int nwb = (N_NODES + 3) / 4;       // 12500 (4 waves/block, wave-per-node)
    int gbl = (N_NODES + 127) / 128;   // 391 (128 rows/block)

    k_count<<<ebl, 256, 0, stream>>>(dst, deg);
    k_scan1<<<nbl, 256, 0, stream>>>(deg, offs, part);
    k_scan2<<<1, 256, 0, stream>>>(part, nbl);
    k_scan3<<<nbl, 256, 0, stream>>>(offs, part);
    k_fill<<<ebl, 256, 0, stream>>>(src, dst, offs, cur, csr);

    // layer 1: node_feats (fp32) -> h1 (bf16); also builds efsum (bf16)
    k_agg_ef<<<nwb, 256, 0, stream>>>((const float2*)node_feats,
                                      (const float2*)edge_feats,
                                      csr, offs, deg, efsum, pre);
    k_gemm<1, 0><<<gbl, 256, 0, stream>>>((const unsigned short*)pre, (const void*)node_feats,
                                          Wn0, Ws0, (void*)h1);
    k_fixup1<<<nwb, 256, 0, stream>>>(node_feats, Wi0, deg, (unsigned short*)h1);

    // layer 2: h1 (bf16) -> d_out (fp32)
    k_agg2<<<nwb, 256, 0, stream>>>(h1, csr, offs, deg, efsum, pre);
    k_gemm<0, 1><<<gbl, 256, 0, stream>>>((const unsigned short*)pre, (const void*)h1,
                                          Wn1, Ws1, d_out);
    k_fixup2<<<nwb, 256, 0, stream>>>((const unsigned short*)h1, Wi1, deg, (float*)d_out);
}